// Round 1
// baseline (395.701 us; speedup 1.0000x reference)
//
#include <hip/hip_runtime.h>
#include <stdint.h>

#define NBOX 4096
#define IMG 640.0f

// ws layout (bytes):
//   [0      .. 16384)  sx1   (4096 f32)
//   [16384  .. 32768)  sy1
//   [32768  .. 49152)  sx2
//   [49152  .. 65536)  sy2
//   [65536  .. 81920)  sconf
//   [81920  .. 81924)  M (int)
//   [81984  .. 82496)  keep words (64 x u64)
//   [131072 .. 2228224) suppression mask (4096*64 u64 = 2 MB)

__global__ __launch_bounds__(256) void k_prep(const float* __restrict__ raw,
                                              float* __restrict__ sx1, float* __restrict__ sy1,
                                              float* __restrict__ sx2, float* __restrict__ sy2,
                                              float* __restrict__ sconf, int* __restrict__ Mp) {
    __shared__ float lconf[NBOX];
    const int t = threadIdx.x;
    const int gid = blockIdx.x * 256 + t;
    for (int k = t; k < NBOX; k += 256) lconf[k] = raw[k * 5 + 4];
    __syncthreads();

    const float ci = lconf[gid];
    const bool vi = (ci >= 0.5f);

    int rank = 0, cnt = 0;
    const float4* l4 = reinterpret_cast<const float4*>(lconf);
#pragma unroll 4
    for (int j4 = 0; j4 < NBOX / 4; ++j4) {
        float4 c = l4[j4];
        int j = j4 * 4;
        {
            bool vj = (c.x >= 0.5f);
            cnt += vj ? 1 : 0;
            rank += (vj && (c.x > ci || (c.x == ci && (j + 0) < gid))) ? 1 : 0;
        }
        {
            bool vj = (c.y >= 0.5f);
            cnt += vj ? 1 : 0;
            rank += (vj && (c.y > ci || (c.y == ci && (j + 1) < gid))) ? 1 : 0;
        }
        {
            bool vj = (c.z >= 0.5f);
            cnt += vj ? 1 : 0;
            rank += (vj && (c.z > ci || (c.z == ci && (j + 2) < gid))) ? 1 : 0;
        }
        {
            bool vj = (c.w >= 0.5f);
            cnt += vj ? 1 : 0;
            rank += (vj && (c.w > ci || (c.w == ci && (j + 3) < gid))) ? 1 : 0;
        }
    }

    if (gid == 0) *Mp = cnt;

    if (vi) {
        // Strict IEEE ops (no FMA contraction) to match the numpy-evaluated reference.
        float cx = __fmul_rn(raw[gid * 5 + 0], IMG);
        float cy = __fmul_rn(raw[gid * 5 + 1], IMG);
        float w  = __fmul_rn(raw[gid * 5 + 2], IMG);
        float h  = __fmul_rn(raw[gid * 5 + 3], IMG);
        float hw = __fmul_rn(w, 0.5f);
        float hh = __fmul_rn(h, 0.5f);
        sx1[rank]   = __fsub_rn(cx, hw);
        sy1[rank]   = __fsub_rn(cy, hh);
        sx2[rank]   = __fadd_rn(cx, hw);
        sy2[rank]   = __fadd_rn(cy, hh);
        sconf[rank] = ci;
    }
}

__global__ __launch_bounds__(256) void k_mask(const float* __restrict__ sx1, const float* __restrict__ sy1,
                                              const float* __restrict__ sx2, const float* __restrict__ sy2,
                                              const int* __restrict__ Mp,
                                              unsigned long long* __restrict__ mask) {
    const int g = blockIdx.x * 256 + threadIdx.x;   // 0 .. 262143
    const int i = g >> 6;
    const int w = g & 63;
    const int M = *Mp;
    if (i >= M) return;

    const float x1 = sx1[i], y1 = sy1[i], x2 = sx2[i], y2 = sy2[i];
    const float area_i = __fmul_rn(__fsub_rn(x2, x1), __fsub_rn(y2, y1));

    unsigned long long bits = 0ULL;
    const int jbase = w << 6;
#pragma unroll 4
    for (int b = 0; b < 64; ++b) {
        const int j = jbase + b;
        if (j <= i || j >= M) continue;
        float xx1 = fmaxf(x1, sx1[j]);
        float yy1 = fmaxf(y1, sy1[j]);
        float xx2 = fminf(x2, sx2[j]);
        float yy2 = fminf(y2, sy2[j]);
        float iw = fmaxf(__fsub_rn(xx2, xx1), 0.0f);
        float ih = fmaxf(__fsub_rn(yy2, yy1), 0.0f);
        float inter = __fmul_rn(iw, ih);
        float area_j = __fmul_rn(__fsub_rn(sx2[j], sx1[j]), __fsub_rn(sy2[j], sy1[j]));
        float uni = __fsub_rn(__fadd_rn(area_i, area_j), inter);
        float iou = __fdiv_rn(inter, fmaxf(uni, 1e-9f));
        if (iou > 0.5f) bits |= (1ULL << b);
    }
    mask[(size_t)i * 64 + w] = bits;
}

__global__ void k_scan(const int* __restrict__ Mp,
                       const unsigned long long* __restrict__ mask,
                       unsigned long long* __restrict__ keepw) {
    const int lane = threadIdx.x;   // 0..63
    const int M = *Mp;
    unsigned long long remv = 0ULL, keep = 0ULL;

    unsigned long long buf[8];
#pragma unroll
    for (int k = 0; k < 8; ++k) buf[k] = (k < M) ? mask[(size_t)k * 64 + lane] : 0ULL;

    for (int base = 0; base < M; base += 8) {
        unsigned long long cur[8];
#pragma unroll
        for (int k = 0; k < 8; ++k) cur[k] = buf[k];
#pragma unroll
        for (int k = 0; k < 8; ++k) {
            int nx = base + 8 + k;
            buf[k] = (nx < M) ? mask[(size_t)nx * 64 + lane] : 0ULL;
        }
#pragma unroll
        for (int k = 0; k < 8; ++k) {
            int i = base + k;
            if (i >= M) break;                       // uniform
            int word = i >> 6, bit = i & 63;
            unsigned long long rw = __shfl(remv, word);   // uniform index -> readlane
            if (!((rw >> bit) & 1ULL)) {             // uniform condition
                remv |= cur[k];
                if (lane == word) keep |= (1ULL << bit);
            }
        }
    }
    keepw[lane] = keep;
}

__global__ __launch_bounds__(256) void k_out(const float* __restrict__ sx1, const float* __restrict__ sy1,
                                             const float* __restrict__ sx2, const float* __restrict__ sy2,
                                             const float* __restrict__ sconf,
                                             const int* __restrict__ Mp,
                                             const unsigned long long* __restrict__ keepw,
                                             float* __restrict__ out) {
    const int g = blockIdx.x * 256 + threadIdx.x;
    if (g >= NBOX * 5) return;
    const int r = g / 5;
    const int c = g - r * 5;
    const int M = *Mp;
    bool kept = false;
    if (r < M) kept = ((keepw[r >> 6] >> (r & 63)) & 1ULL) != 0ULL;
    float v = 0.0f;
    if (kept) {
        const float* arr = (c == 0) ? sx1 : (c == 1) ? sy1 : (c == 2) ? sx2 : (c == 3) ? sy2 : sconf;
        v = arr[r];
    }
    out[g] = v;
}

extern "C" void kernel_launch(void* const* d_in, const int* in_sizes, int n_in,
                              void* d_out, int out_size, void* d_ws, size_t ws_size,
                              hipStream_t stream) {
    const float* raw = (const float*)d_in[0];
    char* ws = (char*)d_ws;
    float* sx1 = (float*)(ws + 0);
    float* sy1 = (float*)(ws + 16384);
    float* sx2 = (float*)(ws + 32768);
    float* sy2 = (float*)(ws + 49152);
    float* sconf = (float*)(ws + 65536);
    int* Mp = (int*)(ws + 81920);
    unsigned long long* keepw = (unsigned long long*)(ws + 81984);
    unsigned long long* mask = (unsigned long long*)(ws + 131072);
    float* out = (float*)d_out;

    k_prep<<<dim3(16), dim3(256), 0, stream>>>(raw, sx1, sy1, sx2, sy2, sconf, Mp);
    k_mask<<<dim3(1024), dim3(256), 0, stream>>>(sx1, sy1, sx2, sy2, Mp, mask);
    k_scan<<<dim3(1), dim3(64), 0, stream>>>(Mp, mask, keepw);
    k_out<<<dim3(80), dim3(256), 0, stream>>>(sx1, sy1, sx2, sy2, sconf, Mp, keepw, out);
}

// Round 2
// 366.825 us; speedup vs baseline: 1.0787x; 1.0787x over previous
//
#include <hip/hip_runtime.h>
#include <stdint.h>

#define NBOX 4096
#define IMG 640.0f

typedef unsigned long long u64;

// ws layout (bytes):
//   [0      .. 16384)   sx1   (4096 f32, sorted)
//   [16384  .. 32768)   sy1
//   [32768  .. 49152)   sx2
//   [49152  .. 65536)   sy2
//   [65536  .. 81920)   sconf
//   [81920  .. 81924)   M (int, atomically accumulated)
//   [82432  .. 82944)   keep words (64 x u64)
//   [86016  .. 118784)  diagT (64 blocks x 64 u64): bit-transposed diagonal blocks
//   [131072 .. 2228224) suppression mask (4096 rows x 64 u64 words = 2 MB)

__global__ __launch_bounds__(256) void k_prep(const float* __restrict__ raw,
                                              float* __restrict__ sx1, float* __restrict__ sy1,
                                              float* __restrict__ sx2, float* __restrict__ sy2,
                                              float* __restrict__ sconf, int* __restrict__ Mp) {
    __shared__ float lconf[NBOX];
    const int t = threadIdx.x;
    const int gid = blockIdx.x * 256 + t;
    for (int k = t; k < NBOX; k += 256) lconf[k] = raw[k * 5 + 4];
    __syncthreads();

    const float ci = lconf[gid];
    const bool vi = (ci >= 0.5f);

    // rank among valid boxes by (conf desc, index asc). For valid i, any j with
    // c_j > ci (>= 0.5) or c_j == ci is automatically valid -> no validity test needed.
    int rank = 0;
    const float4* l4 = reinterpret_cast<const float4*>(lconf);
#pragma unroll 8
    for (int j4 = 0; j4 < NBOX / 4; ++j4) {
        float4 c = l4[j4];
        int j = j4 * 4;
        rank += (c.x > ci || (c.x == ci && (j + 0) < gid)) ? 1 : 0;
        rank += (c.y > ci || (c.y == ci && (j + 1) < gid)) ? 1 : 0;
        rank += (c.z > ci || (c.z == ci && (j + 2) < gid)) ? 1 : 0;
        rank += (c.w > ci || (c.w == ci && (j + 3) < gid)) ? 1 : 0;
    }

    u64 bal = __ballot(vi);
    if ((t & 63) == 0) atomicAdd(Mp, (int)__popcll(bal));

    if (vi) {
        // Strict IEEE ops (no FMA contraction) to match the numpy-evaluated reference.
        float cx = __fmul_rn(raw[gid * 5 + 0], IMG);
        float cy = __fmul_rn(raw[gid * 5 + 1], IMG);
        float w  = __fmul_rn(raw[gid * 5 + 2], IMG);
        float h  = __fmul_rn(raw[gid * 5 + 3], IMG);
        float hw = __fmul_rn(w, 0.5f);
        float hh = __fmul_rn(h, 0.5f);
        sx1[rank]   = __fsub_rn(cx, hw);
        sy1[rank]   = __fsub_rn(cy, hh);
        sx2[rank]   = __fadd_rn(cx, hw);
        sy2[rank]   = __fadd_rn(cy, hh);
        sconf[rank] = ci;
    }
}

// Block (bx, w): rows r = bx*256+tid (lane = row -> coalesced), word w of columns.
// Column boxes staged in LDS (uniform broadcast reads). The wave owning the
// diagonal 64x64 block also emits its bit-transpose via 64 ballots.
__global__ __launch_bounds__(256) void k_mask(const float* __restrict__ sx1, const float* __restrict__ sy1,
                                              const float* __restrict__ sx2, const float* __restrict__ sy2,
                                              const int* __restrict__ Mp,
                                              u64* __restrict__ mask, u64* __restrict__ diagT) {
    const int w = blockIdx.y;                      // column word 0..63
    const int r = blockIdx.x * 256 + threadIdx.x;  // row 0..4095
    const int t = threadIdx.x;
    const int M = *Mp;

    __shared__ float cx1[64], cy1[64], cx2[64], cy2[64], car[64];
    if (t < 64) {
        int j = (w << 6) + t;
        float a1 = sx1[j], b1 = sy1[j], a2 = sx2[j], b2 = sy2[j];
        cx1[t] = a1; cy1[t] = b1; cx2[t] = a2; cy2[t] = b2;
        car[t] = __fmul_rn(__fsub_rn(a2, a1), __fsub_rn(b2, b1));
    }
    __syncthreads();

    u64 bits = 0ULL;
    if (r < M) {
        const float x1 = sx1[r], y1 = sy1[r], x2 = sx2[r], y2 = sy2[r];
        const float area_i = __fmul_rn(__fsub_rn(x2, x1), __fsub_rn(y2, y1));
        const int bmax = min(64, M - (w << 6));       // j < M
        const int bmin = max(0, r + 1 - (w << 6));    // j > r
        for (int b = bmin; b < bmax; ++b) {
            float xx1 = fmaxf(x1, cx1[b]);
            float yy1 = fmaxf(y1, cy1[b]);
            float xx2 = fminf(x2, cx2[b]);
            float yy2 = fminf(y2, cy2[b]);
            float iw = fmaxf(__fsub_rn(xx2, xx1), 0.0f);
            float ih = fmaxf(__fsub_rn(yy2, yy1), 0.0f);
            float inter = __fmul_rn(iw, ih);
            float uni = __fsub_rn(__fadd_rn(area_i, car[b]), inter);
            float iou = __fdiv_rn(inter, fmaxf(uni, 1e-9f));
            if (iou > 0.5f) bits |= (1ULL << b);
        }
        mask[((size_t)r << 6) + w] = bits;
    }

    // diagonal wave: rows [w*64, w*64+64) belong to this wave iff r>>6 == w (wave-uniform)
    if ((r >> 6) == w) {
        const int myj = r & 63;
        u64 colv = 0ULL;
#pragma unroll 1
        for (int j = 0; j < 64; ++j) {
            u64 bb = __ballot((int)((bits >> j) & 1ULL));
            if (myj == j) colv = bb;
        }
        diagT[(w << 6) + myj] = colv;   // bit i = D[i][myj] within the block
    }
}

// One wave. Per 64-box block: greedy scan entirely on uniform masks (one ballot
// per KEPT box), then OR kept rows' mask words into per-lane remv (coalesced).
__global__ void k_scan(const int* __restrict__ Mp,
                       const u64* __restrict__ mask,
                       const u64* __restrict__ diagT,
                       u64* __restrict__ keepw) {
    const int lane = threadIdx.x;   // 0..63, owns remv/keep word `lane`
    const int M = *Mp;
    u64 remv = 0ULL, keep = 0ULL;
    const int nblk = (M + 63) >> 6;

    for (int b = 0; b < nblk; ++b) {
        u64 rb = __shfl(remv, b);                     // suppression word for this block
        u64 col = diagT[(b << 6) + lane];             // column `lane` of diagonal block
        int gi = (b << 6) + lane;
        bool alive0 = (((rb >> lane) & 1ULL) == 0ULL) && (gi < M);
        u64 alive = __ballot(alive0);

        u64 kb = 0ULL;
        for (int i = 0; i < 64; ++i) {
            if ((alive >> i) & 1ULL) {                // uniform SALU test
                kb |= (1ULL << i);
                u64 sup = __ballot((int)((col >> i) & 1ULL));  // row i of diag block
                alive &= ~sup;
            }
        }
        if (lane == b) keep = kb;

        u64 tkb = kb;
        while (tkb) {                                  // OR kept rows into future words
            int i = __builtin_ctzll(tkb);
            tkb &= tkb - 1;
            remv |= mask[((size_t)((b << 6) + i) << 6) + lane];
        }
    }
    keepw[lane] = keep;
}

__global__ __launch_bounds__(256) void k_out(const float* __restrict__ sx1, const float* __restrict__ sy1,
                                             const float* __restrict__ sx2, const float* __restrict__ sy2,
                                             const float* __restrict__ sconf,
                                             const int* __restrict__ Mp,
                                             const u64* __restrict__ keepw,
                                             float* __restrict__ out) {
    const int g = blockIdx.x * 256 + threadIdx.x;
    if (g >= NBOX * 5) return;
    const int r = g / 5;
    const int c = g - r * 5;
    const int M = *Mp;
    bool kept = false;
    if (r < M) kept = ((keepw[r >> 6] >> (r & 63)) & 1ULL) != 0ULL;
    float v = 0.0f;
    if (kept) {
        const float* arr = (c == 0) ? sx1 : (c == 1) ? sy1 : (c == 2) ? sx2 : (c == 3) ? sy2 : sconf;
        v = arr[r];
    }
    out[g] = v;
}

extern "C" void kernel_launch(void* const* d_in, const int* in_sizes, int n_in,
                              void* d_out, int out_size, void* d_ws, size_t ws_size,
                              hipStream_t stream) {
    const float* raw = (const float*)d_in[0];
    char* ws = (char*)d_ws;
    float* sx1 = (float*)(ws + 0);
    float* sy1 = (float*)(ws + 16384);
    float* sx2 = (float*)(ws + 32768);
    float* sy2 = (float*)(ws + 49152);
    float* sconf = (float*)(ws + 65536);
    int* Mp = (int*)(ws + 81920);
    u64* keepw = (u64*)(ws + 82432);
    u64* diagT = (u64*)(ws + 86016);
    u64* mask = (u64*)(ws + 131072);
    float* out = (float*)d_out;

    hipMemsetAsync(Mp, 0, sizeof(int), stream);
    k_prep<<<dim3(16), dim3(256), 0, stream>>>(raw, sx1, sy1, sx2, sy2, sconf, Mp);
    k_mask<<<dim3(16, 64), dim3(256), 0, stream>>>(sx1, sy1, sx2, sy2, Mp, mask, diagT);
    k_scan<<<dim3(1), dim3(64), 0, stream>>>(Mp, mask, diagT, keepw);
    k_out<<<dim3(80), dim3(256), 0, stream>>>(sx1, sy1, sx2, sy2, sconf, Mp, keepw, out);
}

// Round 3
// 211.996 us; speedup vs baseline: 1.8666x; 1.7303x over previous
//
#include <hip/hip_runtime.h>
#include <stdint.h>

#define NBOX 4096
#define IMG 640.0f

typedef unsigned long long u64;

// ws layout (bytes):
//   [0      .. 16384)   sx1   (4096 f32, sorted)
//   [16384  .. 32768)   sy1
//   [32768  .. 49152)   sx2
//   [49152  .. 65536)   sy2
//   [65536  .. 81920)   sconf
//   [81920  .. 81924)   M (int, atomically accumulated)
//   [82432  .. 82944)   keep words (64 x u64)
//   [86016  .. 118784)  diagT (64 blocks x 64 u64): bit-transposed diagonal blocks
//   [131072 .. 2228224) suppression mask (4096 rows x 64 u64 words = 2 MB)

__global__ __launch_bounds__(256) void k_prep(const float* __restrict__ raw,
                                              float* __restrict__ sx1, float* __restrict__ sy1,
                                              float* __restrict__ sx2, float* __restrict__ sy2,
                                              float* __restrict__ sconf, int* __restrict__ Mp) {
    __shared__ float lconf[NBOX];
    const int t = threadIdx.x;
    const int gid = blockIdx.x * 256 + t;
    for (int k = t; k < NBOX; k += 256) lconf[k] = raw[k * 5 + 4];
    __syncthreads();

    const float ci = lconf[gid];
    const bool vi = (ci >= 0.5f);

    int rank = 0;
    const float4* l4 = reinterpret_cast<const float4*>(lconf);
#pragma unroll 8
    for (int j4 = 0; j4 < NBOX / 4; ++j4) {
        float4 c = l4[j4];
        int j = j4 * 4;
        rank += (c.x > ci || (c.x == ci && (j + 0) < gid)) ? 1 : 0;
        rank += (c.y > ci || (c.y == ci && (j + 1) < gid)) ? 1 : 0;
        rank += (c.z > ci || (c.z == ci && (j + 2) < gid)) ? 1 : 0;
        rank += (c.w > ci || (c.w == ci && (j + 3) < gid)) ? 1 : 0;
    }

    u64 bal = __ballot(vi);
    if ((t & 63) == 0) atomicAdd(Mp, (int)__popcll(bal));

    if (vi) {
        // Strict IEEE ops (no FMA contraction) to match the numpy-evaluated reference.
        float cx = __fmul_rn(raw[gid * 5 + 0], IMG);
        float cy = __fmul_rn(raw[gid * 5 + 1], IMG);
        float w  = __fmul_rn(raw[gid * 5 + 2], IMG);
        float h  = __fmul_rn(raw[gid * 5 + 3], IMG);
        float hw = __fmul_rn(w, 0.5f);
        float hh = __fmul_rn(h, 0.5f);
        sx1[rank]   = __fsub_rn(cx, hw);
        sy1[rank]   = __fsub_rn(cy, hh);
        sx2[rank]   = __fadd_rn(cx, hw);
        sy2[rank]   = __fadd_rn(cy, hh);
        sconf[rank] = ci;
    }
}

// Block (bx, w): rows r = bx*256+tid (lane = row -> coalesced), word w of columns.
__global__ __launch_bounds__(256) void k_mask(const float* __restrict__ sx1, const float* __restrict__ sy1,
                                              const float* __restrict__ sx2, const float* __restrict__ sy2,
                                              const int* __restrict__ Mp,
                                              u64* __restrict__ mask, u64* __restrict__ diagT) {
    const int w = blockIdx.y;                      // column word 0..63
    const int r = blockIdx.x * 256 + threadIdx.x;  // row 0..4095
    const int t = threadIdx.x;
    const int M = *Mp;

    __shared__ float cx1[64], cy1[64], cx2[64], cy2[64], car[64];
    if (t < 64) {
        int j = (w << 6) + t;
        float a1 = sx1[j], b1 = sy1[j], a2 = sx2[j], b2 = sy2[j];
        cx1[t] = a1; cy1[t] = b1; cx2[t] = a2; cy2[t] = b2;
        car[t] = __fmul_rn(__fsub_rn(a2, a1), __fsub_rn(b2, b1));
    }
    __syncthreads();

    u64 bits = 0ULL;
    if (r < M) {
        const float x1 = sx1[r], y1 = sy1[r], x2 = sx2[r], y2 = sy2[r];
        const float area_i = __fmul_rn(__fsub_rn(x2, x1), __fsub_rn(y2, y1));
        const int bmax = min(64, M - (w << 6));       // j < M
        const int bmin = max(0, r + 1 - (w << 6));    // j > r
        for (int b = bmin; b < bmax; ++b) {
            float xx1 = fmaxf(x1, cx1[b]);
            float yy1 = fmaxf(y1, cy1[b]);
            float xx2 = fminf(x2, cx2[b]);
            float yy2 = fminf(y2, cy2[b]);
            float iw = fmaxf(__fsub_rn(xx2, xx1), 0.0f);
            float ih = fmaxf(__fsub_rn(yy2, yy1), 0.0f);
            float inter = __fmul_rn(iw, ih);
            float uni = __fsub_rn(__fadd_rn(area_i, car[b]), inter);
            float iou = __fdiv_rn(inter, fmaxf(uni, 1e-9f));
            if (iou > 0.5f) bits |= (1ULL << b);
        }
        mask[((size_t)r << 6) + w] = bits;
    }

    // diagonal wave: emits bit-transpose of its 64x64 diagonal block
    if ((r >> 6) == w) {
        const int myj = r & 63;
        u64 colv = 0ULL;
#pragma unroll 1
        for (int j = 0; j < 64; ++j) {
            u64 bb = __ballot((int)((bits >> j) & 1ULL));
            if (myj == j) colv = bb;
        }
        diagT[(w << 6) + myj] = colv;   // bit i = D[i][myj] within the block
    }
}

// 9 waves: wave 0 = serial greedy scan; waves 1..8 = LDS tile stagers (double buffer).
// Per 64-box block: greedy over uniform 'alive' mask iterating SET BITS only
// (one ballot per KEPT box); kept rows' mask words ORed from the LDS tile.
__global__ __launch_bounds__(576) void k_scan(const int* __restrict__ Mp,
                                              const u64* __restrict__ mask,
                                              const u64* __restrict__ diagT,
                                              u64* __restrict__ keepw) {
    __shared__ u64 tile[2][64 * 64];   // 2 x 32 KB
    const int tid = threadIdx.x;
    const int wave = tid >> 6;
    const int lane = tid & 63;
    const int M = *Mp;
    const int nblk = (M + 63) >> 6;
    if (nblk == 0) return;

    u64 remv = 0ULL;
    u64 col = 0ULL;

    if (wave == 0) {
        col = diagT[lane];                       // block 0 diagonal column
    } else {
        // stage block 0 -> tile[0]: flat 32 KB coalesced copy, 4 x 16B per thread
        const int st = tid - 64;                 // 0..511
        const ulonglong2* src = reinterpret_cast<const ulonglong2*>(mask);
        ulonglong2* dst = reinterpret_cast<ulonglong2*>(tile[0]);
        ulonglong2 v[4];
#pragma unroll
        for (int s = 0; s < 4; ++s) v[s] = src[st + (s << 9)];
#pragma unroll
        for (int s = 0; s < 4; ++s) dst[st + (s << 9)] = v[s];
    }
    __syncthreads();

    for (int b = 0; b < nblk; ++b) {
        if (wave != 0) {
            if (b + 1 < nblk) {                  // stage next block into other buffer
                const int st = tid - 64;
                const ulonglong2* src = reinterpret_cast<const ulonglong2*>(mask + ((size_t)(b + 1) << 12));
                ulonglong2* dst = reinterpret_cast<ulonglong2*>(tile[(b + 1) & 1]);
                ulonglong2 v[4];
#pragma unroll
                for (int s = 0; s < 4; ++s) v[s] = src[st + (s << 9)];
#pragma unroll
                for (int s = 0; s < 4; ++s) dst[st + (s << 9)] = v[s];
            }
        } else {
            // prefetch next block's diagonal column (latency hidden under this block)
            u64 ncol = (b + 1 < nblk) ? diagT[((b + 1) << 6) + lane] : 0ULL;

            u64 rb = __shfl(remv, b);            // suppression word for this block
            bool a0 = (((rb >> lane) & 1ULL) == 0ULL) && (((b << 6) + lane) < M);
            u64 alive = __ballot(a0);

            u64 kb = 0ULL;
            while (alive) {                      // iterate set bits only (uniform SALU)
                int i = __builtin_ctzll(alive);
                alive &= alive - 1;              // clear bit i
                kb |= (1ULL << i);
                u64 sup = __ballot((int)((col >> i) & 1ULL));   // row i of diag block
                alive &= ~sup;                   // sup only has bits > i
            }
            if (lane == 0) keepw[b] = kb;

            // OR kept rows (from LDS tile), 2-wide to keep 2 ds_reads in flight
            u64 acc = 0ULL, t = kb;
            const u64* tb = tile[b & 1];
            while (t) {
                int i0 = __builtin_ctzll(t); t &= t - 1;
                int i1 = -1;
                if (t) { i1 = __builtin_ctzll(t); t &= t - 1; }
                u64 v0 = tb[(i0 << 6) + lane];
                u64 v1 = (i1 >= 0) ? tb[(i1 << 6) + lane] : 0ULL;
                acc |= v0 | v1;
            }
            remv |= acc;
            col = ncol;
        }
        __syncthreads();
    }
}

__global__ __launch_bounds__(256) void k_out(const float* __restrict__ sx1, const float* __restrict__ sy1,
                                             const float* __restrict__ sx2, const float* __restrict__ sy2,
                                             const float* __restrict__ sconf,
                                             const int* __restrict__ Mp,
                                             const u64* __restrict__ keepw,
                                             float* __restrict__ out) {
    const int g = blockIdx.x * 256 + threadIdx.x;
    if (g >= NBOX * 5) return;
    const int r = g / 5;
    const int c = g - r * 5;
    const int M = *Mp;
    bool kept = false;
    if (r < M) kept = ((keepw[r >> 6] >> (r & 63)) & 1ULL) != 0ULL;
    float v = 0.0f;
    if (kept) {
        const float* arr = (c == 0) ? sx1 : (c == 1) ? sy1 : (c == 2) ? sx2 : (c == 3) ? sy2 : sconf;
        v = arr[r];
    }
    out[g] = v;
}

extern "C" void kernel_launch(void* const* d_in, const int* in_sizes, int n_in,
                              void* d_out, int out_size, void* d_ws, size_t ws_size,
                              hipStream_t stream) {
    const float* raw = (const float*)d_in[0];
    char* ws = (char*)d_ws;
    float* sx1 = (float*)(ws + 0);
    float* sy1 = (float*)(ws + 16384);
    float* sx2 = (float*)(ws + 32768);
    float* sy2 = (float*)(ws + 49152);
    float* sconf = (float*)(ws + 65536);
    int* Mp = (int*)(ws + 81920);
    u64* keepw = (u64*)(ws + 82432);
    u64* diagT = (u64*)(ws + 86016);
    u64* mask = (u64*)(ws + 131072);
    float* out = (float*)d_out;

    hipMemsetAsync(Mp, 0, sizeof(int), stream);
    k_prep<<<dim3(16), dim3(256), 0, stream>>>(raw, sx1, sy1, sx2, sy2, sconf, Mp);
    k_mask<<<dim3(16, 64), dim3(256), 0, stream>>>(sx1, sy1, sx2, sy2, Mp, mask, diagT);
    k_scan<<<dim3(1), dim3(576), 0, stream>>>(Mp, mask, diagT, keepw);
    k_out<<<dim3(80), dim3(256), 0, stream>>>(sx1, sy1, sx2, sy2, sconf, Mp, keepw, out);
}

// Round 4
// 104.198 us; speedup vs baseline: 3.7976x; 2.0345x over previous
//
#include <hip/hip_runtime.h>
#include <stdint.h>

#define NBOX 4096
#define IMG 640.0f

typedef unsigned long long u64;

// ws layout (bytes):
//   [0      .. 16384)    sx1   (4096 f32, sorted)
//   [16384  .. 32768)    sy1
//   [32768  .. 49152)    sx2
//   [49152  .. 65536)    sy2
//   [65536  .. 81920)    sconf
//   [81920  .. 81924)    M (int, atomically accumulated)
//   [82432  .. 82944)    keep words (64 x u64)
//   [86016  .. 118784)   diagT (64 blocks x 64 u64): bit-transposed diagonal blocks
//   [131072 .. 2228224)  suppression mask (4096 rows x 64 u64 words = 2 MB)
//   [2228224 .. 2490368) rank_partial (16 x 4096 int = 256 KB)

// Grid (16 i-chunks, 16 j-chunks), 256 thr. Partial rank of i within j-chunk.
__global__ __launch_bounds__(256) void k_rank(const float* __restrict__ raw,
                                              int* __restrict__ rank_partial) {
    const int bi = blockIdx.x, bj = blockIdx.y;
    const int t = threadIdx.x;
    const int i = bi * 256 + t;
    __shared__ float cj[256];
    cj[t] = raw[(bj * 256 + t) * 5 + 4];
    __syncthreads();

    const float ci = raw[i * 5 + 4];
    const int jbase = bj * 256;
    int rank = 0;
    const float4* c4 = reinterpret_cast<const float4*>(cj);
#pragma unroll 4
    for (int j4 = 0; j4 < 64; ++j4) {
        float4 c = c4[j4];
        int j = jbase + j4 * 4;
        rank += (c.x > ci || (c.x == ci && (j + 0) < i)) ? 1 : 0;
        rank += (c.y > ci || (c.y == ci && (j + 1) < i)) ? 1 : 0;
        rank += (c.z > ci || (c.z == ci && (j + 2) < i)) ? 1 : 0;
        rank += (c.w > ci || (c.w == ci && (j + 3) < i)) ? 1 : 0;
    }
    rank_partial[bj * NBOX + i] = rank;
}

__global__ __launch_bounds__(256) void k_scatter(const float* __restrict__ raw,
                                                 const int* __restrict__ rank_partial,
                                                 float* __restrict__ sx1, float* __restrict__ sy1,
                                                 float* __restrict__ sx2, float* __restrict__ sy2,
                                                 float* __restrict__ sconf, int* __restrict__ Mp) {
    const int i = blockIdx.x * 256 + threadIdx.x;
    const float ci = raw[i * 5 + 4];
    const bool vi = (ci >= 0.5f);

    int rank = 0;
#pragma unroll
    for (int k = 0; k < 16; ++k) rank += rank_partial[k * NBOX + i];

    u64 bal = __ballot(vi);
    if ((threadIdx.x & 63) == 0) atomicAdd(Mp, (int)__popcll(bal));

    if (vi) {
        // Strict IEEE ops (no FMA contraction) to match the numpy-evaluated reference.
        float cx = __fmul_rn(raw[i * 5 + 0], IMG);
        float cy = __fmul_rn(raw[i * 5 + 1], IMG);
        float w  = __fmul_rn(raw[i * 5 + 2], IMG);
        float h  = __fmul_rn(raw[i * 5 + 3], IMG);
        float hw = __fmul_rn(w, 0.5f);
        float hh = __fmul_rn(h, 0.5f);
        sx1[rank]   = __fsub_rn(cx, hw);
        sy1[rank]   = __fsub_rn(cy, hh);
        sx2[rank]   = __fadd_rn(cx, hw);
        sy2[rank]   = __fadd_rn(cy, hh);
        sconf[rank] = ci;
    }
}

// Block (bx, w): rows r = bx*256+tid (lane = row -> coalesced), word w of columns.
__global__ __launch_bounds__(256) void k_mask(const float* __restrict__ sx1, const float* __restrict__ sy1,
                                              const float* __restrict__ sx2, const float* __restrict__ sy2,
                                              const int* __restrict__ Mp,
                                              u64* __restrict__ mask, u64* __restrict__ diagT) {
    const int w = blockIdx.y;                      // column word 0..63
    const int r = blockIdx.x * 256 + threadIdx.x;  // row 0..4095
    const int t = threadIdx.x;
    const int M = *Mp;

    __shared__ float cx1[64], cy1[64], cx2[64], cy2[64], car[64];
    if (t < 64) {
        int j = (w << 6) + t;
        float a1 = sx1[j], b1 = sy1[j], a2 = sx2[j], b2 = sy2[j];
        cx1[t] = a1; cy1[t] = b1; cx2[t] = a2; cy2[t] = b2;
        car[t] = __fmul_rn(__fsub_rn(a2, a1), __fsub_rn(b2, b1));
    }
    __syncthreads();

    u64 bits = 0ULL;
    if (r < M) {
        const float x1 = sx1[r], y1 = sy1[r], x2 = sx2[r], y2 = sy2[r];
        const float area_i = __fmul_rn(__fsub_rn(x2, x1), __fsub_rn(y2, y1));
        const int bmax = min(64, M - (w << 6));       // j < M
        const int bmin = max(0, r + 1 - (w << 6));    // j > r
        for (int b = bmin; b < bmax; ++b) {
            float xx1 = fmaxf(x1, cx1[b]);
            float yy1 = fmaxf(y1, cy1[b]);
            float xx2 = fminf(x2, cx2[b]);
            float yy2 = fminf(y2, cy2[b]);
            float iw = fmaxf(__fsub_rn(xx2, xx1), 0.0f);
            float ih = fmaxf(__fsub_rn(yy2, yy1), 0.0f);
            float inter = __fmul_rn(iw, ih);
            float uni = __fsub_rn(__fadd_rn(area_i, car[b]), inter);
            float iou = __fdiv_rn(inter, fmaxf(uni, 1e-9f));
            if (iou > 0.5f) bits |= (1ULL << b);
        }
        mask[((size_t)r << 6) + w] = bits;
    }

    // diagonal wave: emits bit-transpose of its 64x64 diagonal block
    if ((r >> 6) == w) {
        const int myj = r & 63;
        u64 colv = 0ULL;
#pragma unroll 1
        for (int j = 0; j < 64; ++j) {
            u64 bb = __ballot((int)((bits >> j) & 1ULL));
            if (myj == j) colv = bb;
        }
        diagT[(w << 6) + myj] = colv;   // bit i = D[i][myj] within the block
    }
}

// 9 waves: wave 0 = serial greedy scan; waves 1..8 = LDS tile stagers (double buffer).
__global__ __launch_bounds__(576) void k_scan(const int* __restrict__ Mp,
                                              const u64* __restrict__ mask,
                                              const u64* __restrict__ diagT,
                                              u64* __restrict__ keepw) {
    __shared__ u64 tile[2][64 * 64];   // 2 x 32 KB
    const int tid = threadIdx.x;
    const int wave = tid >> 6;
    const int lane = tid & 63;
    const int M = *Mp;
    const int nblk = (M + 63) >> 6;
    if (nblk == 0) return;

    u64 remv = 0ULL;
    u64 col = 0ULL;

    if (wave == 0) {
        col = diagT[lane];                       // block 0 diagonal column
    } else {
        const int st = tid - 64;                 // 0..511
        const ulonglong2* src = reinterpret_cast<const ulonglong2*>(mask);
        ulonglong2* dst = reinterpret_cast<ulonglong2*>(tile[0]);
        ulonglong2 v[4];
#pragma unroll
        for (int s = 0; s < 4; ++s) v[s] = src[st + (s << 9)];
#pragma unroll
        for (int s = 0; s < 4; ++s) dst[st + (s << 9)] = v[s];
    }
    __syncthreads();

    for (int b = 0; b < nblk; ++b) {
        if (wave != 0) {
            if (b + 1 < nblk) {
                const int st = tid - 64;
                const ulonglong2* src = reinterpret_cast<const ulonglong2*>(mask + ((size_t)(b + 1) << 12));
                ulonglong2* dst = reinterpret_cast<ulonglong2*>(tile[(b + 1) & 1]);
                ulonglong2 v[4];
#pragma unroll
                for (int s = 0; s < 4; ++s) v[s] = src[st + (s << 9)];
#pragma unroll
                for (int s = 0; s < 4; ++s) dst[st + (s << 9)] = v[s];
            }
        } else {
            u64 ncol = (b + 1 < nblk) ? diagT[((b + 1) << 6) + lane] : 0ULL;

            u64 rb = __shfl(remv, b);            // suppression word for this block
            bool a0 = (((rb >> lane) & 1ULL) == 0ULL) && (((b << 6) + lane) < M);
            u64 alive = __ballot(a0);

            u64 kb = 0ULL;
            while (alive) {                      // iterate set bits only (uniform SALU)
                int i = __builtin_ctzll(alive);
                alive &= alive - 1;
                kb |= (1ULL << i);
                u64 sup = __ballot((int)((col >> i) & 1ULL));   // row i of diag block
                alive &= ~sup;
            }
            if (lane == 0) keepw[b] = kb;

            u64 acc = 0ULL, t = kb;
            const u64* tb = tile[b & 1];
            while (t) {
                int i0 = __builtin_ctzll(t); t &= t - 1;
                int i1 = -1;
                if (t) { i1 = __builtin_ctzll(t); t &= t - 1; }
                u64 v0 = tb[(i0 << 6) + lane];
                u64 v1 = (i1 >= 0) ? tb[(i1 << 6) + lane] : 0ULL;
                acc |= v0 | v1;
            }
            remv |= acc;
            col = ncol;
        }
        __syncthreads();
    }
}

__global__ __launch_bounds__(256) void k_out(const float* __restrict__ sx1, const float* __restrict__ sy1,
                                             const float* __restrict__ sx2, const float* __restrict__ sy2,
                                             const float* __restrict__ sconf,
                                             const int* __restrict__ Mp,
                                             const u64* __restrict__ keepw,
                                             float* __restrict__ out) {
    const int g = blockIdx.x * 256 + threadIdx.x;
    if (g >= NBOX * 5) return;
    const int r = g / 5;
    const int c = g - r * 5;
    const int M = *Mp;
    bool kept = false;
    if (r < M) kept = ((keepw[r >> 6] >> (r & 63)) & 1ULL) != 0ULL;
    float v = 0.0f;
    if (kept) {
        const float* arr = (c == 0) ? sx1 : (c == 1) ? sy1 : (c == 2) ? sx2 : (c == 3) ? sy2 : sconf;
        v = arr[r];
    }
    out[g] = v;
}

extern "C" void kernel_launch(void* const* d_in, const int* in_sizes, int n_in,
                              void* d_out, int out_size, void* d_ws, size_t ws_size,
                              hipStream_t stream) {
    const float* raw = (const float*)d_in[0];
    char* ws = (char*)d_ws;
    float* sx1 = (float*)(ws + 0);
    float* sy1 = (float*)(ws + 16384);
    float* sx2 = (float*)(ws + 32768);
    float* sy2 = (float*)(ws + 49152);
    float* sconf = (float*)(ws + 65536);
    int* Mp = (int*)(ws + 81920);
    u64* keepw = (u64*)(ws + 82432);
    u64* diagT = (u64*)(ws + 86016);
    u64* mask = (u64*)(ws + 131072);
    int* rank_partial = (int*)(ws + 2228224);
    float* out = (float*)d_out;

    hipMemsetAsync(Mp, 0, sizeof(int), stream);
    k_rank<<<dim3(16, 16), dim3(256), 0, stream>>>(raw, rank_partial);
    k_scatter<<<dim3(16), dim3(256), 0, stream>>>(raw, rank_partial, sx1, sy1, sx2, sy2, sconf, Mp);
    k_mask<<<dim3(16, 64), dim3(256), 0, stream>>>(sx1, sy1, sx2, sy2, Mp, mask, diagT);
    k_scan<<<dim3(1), dim3(576), 0, stream>>>(Mp, mask, diagT, keepw);
    k_out<<<dim3(80), dim3(256), 0, stream>>>(sx1, sy1, sx2, sy2, sconf, Mp, keepw, out);
}

// Round 5
// 93.512 us; speedup vs baseline: 4.2316x; 1.1143x over previous
//
#include <hip/hip_runtime.h>
#include <stdint.h>

#define NBOX 4096
#define IMG 640.0f

typedef unsigned long long u64;

// ws layout (bytes):
//   [0      .. 16384)    sx1   (4096 f32, sorted)
//   [16384  .. 32768)    sy1
//   [32768  .. 49152)    sx2
//   [49152  .. 65536)    sy2
//   [65536  .. 81920)    sconf
//   [81920  .. 81924)    M (int, atomically accumulated; zeroed by k_rank blk(0,0))
//   [82432  .. 82944)    keep words (64 x u64)
//   [86016  .. 118784)   diagT (64 blocks x 64 u64): bit-transposed diagonal blocks
//   [131072 .. 2228224)  suppression mask (4096 rows x 64 u64 words = 2 MB)
//   [2228224 .. 2490368) rank_partial (16 x 4096 int = 256 KB)

// Grid (16 i-chunks, 16 j-chunks), 256 thr. Partial rank of i within j-chunk.
__global__ __launch_bounds__(256) void k_rank(const float* __restrict__ raw,
                                              int* __restrict__ rank_partial, int* __restrict__ Mp) {
    const int bi = blockIdx.x, bj = blockIdx.y;
    const int t = threadIdx.x;
    const int i = bi * 256 + t;
    if (bi == 0 && bj == 0 && t == 0) *Mp = 0;   // k_scatter (next kernel) accumulates
    __shared__ float cj[256];
    cj[t] = raw[(bj * 256 + t) * 5 + 4];
    __syncthreads();

    const float ci = raw[i * 5 + 4];
    const int jbase = bj * 256;
    int rank = 0;
    const float4* c4 = reinterpret_cast<const float4*>(cj);
#pragma unroll 4
    for (int j4 = 0; j4 < 64; ++j4) {
        float4 c = c4[j4];
        int j = jbase + j4 * 4;
        rank += (c.x > ci || (c.x == ci && (j + 0) < i)) ? 1 : 0;
        rank += (c.y > ci || (c.y == ci && (j + 1) < i)) ? 1 : 0;
        rank += (c.z > ci || (c.z == ci && (j + 2) < i)) ? 1 : 0;
        rank += (c.w > ci || (c.w == ci && (j + 3) < i)) ? 1 : 0;
    }
    rank_partial[bj * NBOX + i] = rank;
}

__global__ __launch_bounds__(256) void k_scatter(const float* __restrict__ raw,
                                                 const int* __restrict__ rank_partial,
                                                 float* __restrict__ sx1, float* __restrict__ sy1,
                                                 float* __restrict__ sx2, float* __restrict__ sy2,
                                                 float* __restrict__ sconf, int* __restrict__ Mp) {
    const int i = blockIdx.x * 256 + threadIdx.x;
    const float ci = raw[i * 5 + 4];
    const bool vi = (ci >= 0.5f);

    int rank = 0;
#pragma unroll
    for (int k = 0; k < 16; ++k) rank += rank_partial[k * NBOX + i];

    u64 bal = __ballot(vi);
    if ((threadIdx.x & 63) == 0) atomicAdd(Mp, (int)__popcll(bal));

    if (vi) {
        // Strict IEEE ops (no FMA contraction) to match the numpy-evaluated reference.
        float cx = __fmul_rn(raw[i * 5 + 0], IMG);
        float cy = __fmul_rn(raw[i * 5 + 1], IMG);
        float w  = __fmul_rn(raw[i * 5 + 2], IMG);
        float h  = __fmul_rn(raw[i * 5 + 3], IMG);
        float hw = __fmul_rn(w, 0.5f);
        float hh = __fmul_rn(h, 0.5f);
        sx1[rank]   = __fsub_rn(cx, hw);
        sy1[rank]   = __fsub_rn(cy, hh);
        sx2[rank]   = __fadd_rn(cx, hw);
        sy2[rank]   = __fadd_rn(cy, hh);
        sconf[rank] = ci;
    }
}

// Block (bx, w): rows r = bx*256+tid (lane = row -> coalesced), word w of columns.
__global__ __launch_bounds__(256) void k_mask(const float* __restrict__ sx1, const float* __restrict__ sy1,
                                              const float* __restrict__ sx2, const float* __restrict__ sy2,
                                              const int* __restrict__ Mp,
                                              u64* __restrict__ mask, u64* __restrict__ diagT) {
    const int w = blockIdx.y;                      // column word 0..63
    const int r = blockIdx.x * 256 + threadIdx.x;  // row 0..4095
    const int t = threadIdx.x;
    const int M = *Mp;

    __shared__ float cx1[64], cy1[64], cx2[64], cy2[64], car[64];
    if (t < 64) {
        int j = (w << 6) + t;
        float a1 = sx1[j], b1 = sy1[j], a2 = sx2[j], b2 = sy2[j];
        cx1[t] = a1; cy1[t] = b1; cx2[t] = a2; cy2[t] = b2;
        car[t] = __fmul_rn(__fsub_rn(a2, a1), __fsub_rn(b2, b1));
    }
    __syncthreads();

    u64 bits = 0ULL;
    if (r < M) {
        const float x1 = sx1[r], y1 = sy1[r], x2 = sx2[r], y2 = sy2[r];
        const float area_i = __fmul_rn(__fsub_rn(x2, x1), __fsub_rn(y2, y1));
        const int bmax = min(64, M - (w << 6));       // j < M
        const int bmin = max(0, r + 1 - (w << 6));    // j > r
        for (int b = bmin; b < bmax; ++b) {
            float xx1 = fmaxf(x1, cx1[b]);
            float yy1 = fmaxf(y1, cy1[b]);
            float xx2 = fminf(x2, cx2[b]);
            float yy2 = fminf(y2, cy2[b]);
            float iw = fmaxf(__fsub_rn(xx2, xx1), 0.0f);
            float ih = fmaxf(__fsub_rn(yy2, yy1), 0.0f);
            float inter = __fmul_rn(iw, ih);
            float uni = __fsub_rn(__fadd_rn(area_i, car[b]), inter);
            float iou = __fdiv_rn(inter, fmaxf(uni, 1e-9f));
            if (iou > 0.5f) bits |= (1ULL << b);
        }
        mask[((size_t)r << 6) + w] = bits;
    }

    // diagonal wave: emits bit-transpose of its 64x64 diagonal block
    if ((r >> 6) == w) {
        const int myj = r & 63;
        u64 colv = 0ULL;
#pragma unroll 1
        for (int j = 0; j < 64; ++j) {
            u64 bb = __ballot((int)((bits >> j) & 1ULL));
            if (myj == j) colv = bb;
        }
        diagT[(w << 6) + myj] = colv;   // bit i = D[i][myj] within the block
    }
}

#define DEPTH 4       // LDS ring slots (power of 2)
#define LOOKAHEAD 3   // blocks issued ahead

#define GLDS(gp, lp)  __builtin_amdgcn_global_load_lds( \
    (const __attribute__((address_space(1))) void*)(gp), \
    (__attribute__((address_space(3))) void*)(lp), 16, 0, 0)

// 9 waves: wave 0 = serial greedy scan; waves 1..8 = async stagers via
// global_load_lds + counted vmcnt + RAW s_barrier (no vmcnt(0) drain in the
// steady-state loop -> loads for blocks b+2..b+3 stay in flight across barriers).
__global__ __launch_bounds__(576) void k_scan(const int* __restrict__ Mp,
                                              const u64* __restrict__ mask,
                                              const u64* __restrict__ diagT,
                                              u64* __restrict__ keepw) {
    __shared__ u64 tile[DEPTH][64 * 64];   // 4 x 32 KB = 128 KB
    const int tid = threadIdx.x;
    const int wave = tid >> 6;
    const int lane = tid & 63;
    const int M = *Mp;
    const int nblk = (M + 63) >> 6;
    if (nblk == 0) return;

    if (wave == 0) {
        __builtin_amdgcn_s_setprio(1);           // wave 0 is the critical path
        u64 remv = 0ULL;
        u64 col = diagT[lane];                   // block 0 diagonal column
        __builtin_amdgcn_s_barrier();            // matches stager prologue barrier
        for (int b = 0; b < nblk; ++b) {
            __builtin_amdgcn_sched_barrier(0);
            u64 ncol = (b + 1 < nblk) ? diagT[((b + 1) << 6) + lane] : 0ULL;

            u64 rb = __shfl(remv, b);            // suppression word for this block
            bool a0 = (((rb >> lane) & 1ULL) == 0ULL) && (((b << 6) + lane) < M);
            u64 alive = __ballot(a0);

            u64 kb = 0ULL;
            while (alive) {                      // iterate set bits only (uniform SALU)
                int i = __builtin_ctzll(alive);
                alive &= alive - 1;
                kb |= (1ULL << i);
                u64 sup = __ballot((int)((col >> i) & 1ULL));   // row i of diag block
                alive &= ~sup;                   // sup only has bits > i
            }
            if (lane == 0) keepw[b] = kb;

            const u64* tb = tile[b & (DEPTH - 1)];
            u64 acc = 0ULL, t = kb;
            while (t) {                          // OR kept rows from LDS, 2-wide
                int i0 = __builtin_ctzll(t); t &= t - 1;
                int i1 = -1;
                if (t) { i1 = __builtin_ctzll(t); t &= t - 1; }
                u64 v0 = tb[(i0 << 6) + lane];
                u64 v1 = (i1 >= 0) ? tb[(i1 << 6) + lane] : 0ULL;
                acc |= v0 | v1;
            }
            remv |= acc;
            col = ncol;
            __builtin_amdgcn_s_barrier();
        }
    } else {
        // stager wave w (1..8): owns 4 KB chunk (w-1) of each 32 KB block tile.
        const char* mb = (const char*)mask;
        const int w1 = wave - 1;
        char* lbase = (char*)&tile[0][0];

        // prologue: issue blocks 0..LOOKAHEAD-1, drain once, barrier.
        for (int blk = 0; blk < LOOKAHEAD && blk < nblk; ++blk) {
            const char* g = mb + ((size_t)blk << 15) + (w1 << 12) + (lane << 4);
            char* l = lbase + ((size_t)(blk & (DEPTH - 1)) << 15) + (w1 << 12);
#pragma unroll
            for (int c = 0; c < 4; ++c) GLDS(g + (c << 10), l + (c << 10));
        }
        asm volatile("s_waitcnt vmcnt(0)" ::: "memory");
        __builtin_amdgcn_s_barrier();

        for (int b = 0; b < nblk; ++b) {
            __builtin_amdgcn_sched_barrier(0);
            const int nb = b + LOOKAHEAD;
            if (nb < nblk) {
                // slot (nb & 3) == ((b-1) & 3): wave 0 finished it last iteration.
                const char* g = mb + ((size_t)nb << 15) + (w1 << 12) + (lane << 4);
                char* l = lbase + ((size_t)(nb & (DEPTH - 1)) << 15) + (w1 << 12);
#pragma unroll
                for (int c = 0; c < 4; ++c) GLDS(g + (c << 10), l + (c << 10));
                // need block b+1 landed; keep last 2 blocks (8 loads) in flight.
                asm volatile("s_waitcnt vmcnt(8)" ::: "memory");
            } else {
                asm volatile("s_waitcnt vmcnt(0)" ::: "memory");   // tail: cheap, long since issued
            }
            __builtin_amdgcn_s_barrier();
        }
    }
}

__global__ __launch_bounds__(256) void k_out(const float* __restrict__ sx1, const float* __restrict__ sy1,
                                             const float* __restrict__ sx2, const float* __restrict__ sy2,
                                             const float* __restrict__ sconf,
                                             const int* __restrict__ Mp,
                                             const u64* __restrict__ keepw,
                                             float* __restrict__ out) {
    const int g = blockIdx.x * 256 + threadIdx.x;
    if (g >= NBOX * 5) return;
    const int r = g / 5;
    const int c = g - r * 5;
    const int M = *Mp;
    bool kept = false;
    if (r < M) kept = ((keepw[r >> 6] >> (r & 63)) & 1ULL) != 0ULL;
    float v = 0.0f;
    if (kept) {
        const float* arr = (c == 0) ? sx1 : (c == 1) ? sy1 : (c == 2) ? sx2 : (c == 3) ? sy2 : sconf;
        v = arr[r];
    }
    out[g] = v;
}

extern "C" void kernel_launch(void* const* d_in, const int* in_sizes, int n_in,
                              void* d_out, int out_size, void* d_ws, size_t ws_size,
                              hipStream_t stream) {
    const float* raw = (const float*)d_in[0];
    char* ws = (char*)d_ws;
    float* sx1 = (float*)(ws + 0);
    float* sy1 = (float*)(ws + 16384);
    float* sx2 = (float*)(ws + 32768);
    float* sy2 = (float*)(ws + 49152);
    float* sconf = (float*)(ws + 65536);
    int* Mp = (int*)(ws + 81920);
    u64* keepw = (u64*)(ws + 82432);
    u64* diagT = (u64*)(ws + 86016);
    u64* mask = (u64*)(ws + 131072);
    int* rank_partial = (int*)(ws + 2228224);
    float* out = (float*)d_out;

    k_rank<<<dim3(16, 16), dim3(256), 0, stream>>>(raw, rank_partial, Mp);
    k_scatter<<<dim3(16), dim3(256), 0, stream>>>(raw, rank_partial, sx1, sy1, sx2, sy2, sconf, Mp);
    k_mask<<<dim3(16, 64), dim3(256), 0, stream>>>(sx1, sy1, sx2, sy2, Mp, mask, diagT);
    k_scan<<<dim3(1), dim3(576), 0, stream>>>(Mp, mask, diagT, keepw);
    k_out<<<dim3(80), dim3(256), 0, stream>>>(sx1, sy1, sx2, sy2, sconf, Mp, keepw, out);
}

// Round 7
// 91.620 us; speedup vs baseline: 4.3189x; 1.0206x over previous
//
#include <hip/hip_runtime.h>
#include <stdint.h>

#define NBOX 4096
#define IMG 640.0f

typedef unsigned long long u64;
typedef unsigned int u32;

// ws layout (bytes):
//   [0      .. 16384)    sx1   (4096 f32, sorted)
//   [16384  .. 32768)    sy1
//   [32768  .. 49152)    sx2
//   [49152  .. 65536)    sy2
//   [65536  .. 81920)    sconf
//   [81920  .. 81924)    M (int, zeroed by k_rank blk(0,0); k_scatter accumulates)
//   [82432  .. 82944)    keep words (64 x u64)
//   [86016  .. 118784)   diagR (4096 u64): row r's suppression word within its own diagonal block
//   [131072 .. 2228224)  suppression mask (4096 rows x 64 u64 words = 2 MB)
//   [2228224 .. 2490368) rank_partial (16 x 4096 int = 256 KB)

// Grid (16 i-chunks, 16 j-chunks), 256 thr. Partial rank of i within j-chunk.
__global__ __launch_bounds__(256) void k_rank(const float* __restrict__ raw,
                                              int* __restrict__ rank_partial, int* __restrict__ Mp) {
    const int bi = blockIdx.x, bj = blockIdx.y;
    const int t = threadIdx.x;
    const int i = bi * 256 + t;
    if (bi == 0 && bj == 0 && t == 0) *Mp = 0;
    __shared__ float cj[256];
    cj[t] = raw[(bj * 256 + t) * 5 + 4];
    __syncthreads();

    const float ci = raw[i * 5 + 4];
    const int jbase = bj * 256;
    int rank = 0;
    const float4* c4 = reinterpret_cast<const float4*>(cj);
#pragma unroll 4
    for (int j4 = 0; j4 < 64; ++j4) {
        float4 c = c4[j4];
        int j = jbase + j4 * 4;
        rank += (c.x > ci || (c.x == ci && (j + 0) < i)) ? 1 : 0;
        rank += (c.y > ci || (c.y == ci && (j + 1) < i)) ? 1 : 0;
        rank += (c.z > ci || (c.z == ci && (j + 2) < i)) ? 1 : 0;
        rank += (c.w > ci || (c.w == ci && (j + 3) < i)) ? 1 : 0;
    }
    rank_partial[bj * NBOX + i] = rank;
}

__global__ __launch_bounds__(256) void k_scatter(const float* __restrict__ raw,
                                                 const int* __restrict__ rank_partial,
                                                 float* __restrict__ sx1, float* __restrict__ sy1,
                                                 float* __restrict__ sx2, float* __restrict__ sy2,
                                                 float* __restrict__ sconf, int* __restrict__ Mp) {
    const int i = blockIdx.x * 256 + threadIdx.x;
    const float ci = raw[i * 5 + 4];
    const bool vi = (ci >= 0.5f);

    int rank = 0;
#pragma unroll
    for (int k = 0; k < 16; ++k) rank += rank_partial[k * NBOX + i];

    u64 bal = __ballot(vi);
    if ((threadIdx.x & 63) == 0) atomicAdd(Mp, (int)__popcll(bal));

    if (vi) {
        // Strict IEEE ops (no FMA contraction) to match the numpy-evaluated reference.
        float cx = __fmul_rn(raw[i * 5 + 0], IMG);
        float cy = __fmul_rn(raw[i * 5 + 1], IMG);
        float w  = __fmul_rn(raw[i * 5 + 2], IMG);
        float h  = __fmul_rn(raw[i * 5 + 3], IMG);
        float hw = __fmul_rn(w, 0.5f);
        float hh = __fmul_rn(h, 0.5f);
        sx1[rank]   = __fsub_rn(cx, hw);
        sy1[rank]   = __fsub_rn(cy, hh);
        sx2[rank]   = __fadd_rn(cx, hw);
        sy2[rank]   = __fadd_rn(cy, hh);
        sconf[rank] = ci;
    }
}

// Block (bx, w): rows r = bx*256+tid (lane = row -> coalesced), word w of columns.
__global__ __launch_bounds__(256) void k_mask(const float* __restrict__ sx1, const float* __restrict__ sy1,
                                              const float* __restrict__ sx2, const float* __restrict__ sy2,
                                              const int* __restrict__ Mp,
                                              u64* __restrict__ mask, u64* __restrict__ diagR) {
    const int w = blockIdx.y;                      // column word 0..63
    const int r = blockIdx.x * 256 + threadIdx.x;  // row 0..4095
    const int t = threadIdx.x;
    const int M = *Mp;

    __shared__ float cx1[64], cy1[64], cx2[64], cy2[64], car[64];
    if (t < 64) {
        int j = (w << 6) + t;
        float a1 = sx1[j], b1 = sy1[j], a2 = sx2[j], b2 = sy2[j];
        cx1[t] = a1; cy1[t] = b1; cx2[t] = a2; cy2[t] = b2;
        car[t] = __fmul_rn(__fsub_rn(a2, a1), __fsub_rn(b2, b1));
    }
    __syncthreads();

    u64 bits = 0ULL;
    if (r < M) {
        const float x1 = sx1[r], y1 = sy1[r], x2 = sx2[r], y2 = sy2[r];
        const float area_i = __fmul_rn(__fsub_rn(x2, x1), __fsub_rn(y2, y1));
        const int bmax = min(64, M - (w << 6));       // j < M
        const int bmin = max(0, r + 1 - (w << 6));    // j > r
        for (int b = bmin; b < bmax; ++b) {
            float xx1 = fmaxf(x1, cx1[b]);
            float yy1 = fmaxf(y1, cy1[b]);
            float xx2 = fminf(x2, cx2[b]);
            float yy2 = fminf(y2, cy2[b]);
            float iw = fmaxf(__fsub_rn(xx2, xx1), 0.0f);
            float ih = fmaxf(__fsub_rn(yy2, yy1), 0.0f);
            float inter = __fmul_rn(iw, ih);
            float uni = __fsub_rn(__fadd_rn(area_i, car[b]), inter);
            float iou = __fdiv_rn(inter, fmaxf(uni, 1e-9f));
            if (iou > 0.5f) bits |= (1ULL << b);
        }
        mask[((size_t)r << 6) + w] = bits;
    }

    // diagonal block: row r's own-word suppression bits (only bits > r within block)
    if ((r >> 6) == w) diagR[r] = bits;
}

// 9 waves, 1 KiB LDS, one barrier per 64-box block. Per iteration b:
//   wave 0 : resolve block b (scalar readlane over prefetched diagR rows) using
//            remvArr[b] | carry; compute carry->word b+1 from register-prefetched
//            column; write kbArr[b], keepw[b].
//   waves 1-8: propagate block b-1's kept rows into remvArr[b+1..63] reading the
//            GLOBAL mask (L2/L3-resident, coalesced, off the critical path).
// Disjoint addresses per iteration -> race-free with a single barrier.
__global__ __launch_bounds__(576) void k_scan(const int* __restrict__ Mp,
                                              const u64* __restrict__ mask,
                                              const u64* __restrict__ diagR,
                                              u64* __restrict__ keepw) {
    __shared__ u64 remvArr[64];
    __shared__ u64 kbArr[64];
    const int tid = threadIdx.x;
    const int wave = tid >> 6;
    const int lane = tid & 63;
    const int M = *Mp;
    const int nblk = (M + 63) >> 6;
    if (nblk == 0) return;

    if (tid < 64) remvArr[tid] = 0ULL;   // wave 0 writes; it is also the first reader

    if (wave == 0) {
        __builtin_amdgcn_s_setprio(1);               // critical-path wave
        u64 rv = diagR[lane];                        // block 0 diag rows
        u32 rlo = (u32)rv, rhi = (u32)(rv >> 32);
        u64 colv = (nblk > 1) ? mask[((size_t)lane << 6) + 1] : 0ULL;  // col 1 of block 0
        u64 carry = 0ULL;                            // block (b-1) -> word b suppression

        for (int b = 0; b < nblk; ++b) {
            u64 rb = remvArr[b];                     // complete: blocks <= b-2 via bg, b-1 via carry
            const int rem = M - (b << 6);
            const u64 valid = (rem >= 64) ? ~0ULL : ((1ULL << rem) - 1ULL);
            u64 alive = valid & ~(rb | carry);
            u64 kb = 0ULL;
            while (alive) {                          // uniform; iterate kept boxes only
                int i = __builtin_ctzll(alive);
                alive &= alive - 1;
                kb |= (1ULL << i);
                u32 lo = __builtin_amdgcn_readlane(rlo, i);
                u32 hi = __builtin_amdgcn_readlane(rhi, i);
                alive &= ~(((u64)hi << 32) | (u64)lo);   // row i: bits only > i
            }
            if (lane == 0) { kbArr[b] = kb; keepw[b] = kb; }

            // carry -> word b+1 from this block's kept rows (colv prefetched last iter)
            u64 nc = ((kb >> lane) & 1ULL) ? colv : 0ULL;
            nc |= __shfl_xor(nc, 1);
            nc |= __shfl_xor(nc, 2);
            nc |= __shfl_xor(nc, 4);
            nc |= __shfl_xor(nc, 8);
            nc |= __shfl_xor(nc, 16);
            nc |= __shfl_xor(nc, 32);
            carry = nc;

            // prefetch block b+1's diag rows + its carry column (b+2); hidden 1 iter
            if (b + 1 < nblk) {
                u64 nrv = diagR[((b + 1) << 6) + lane];
                rlo = (u32)nrv; rhi = (u32)(nrv >> 32);
                colv = (b + 2 < nblk)
                     ? mask[(((size_t)(b + 1) << 6) + lane) * 64 + (b + 2)]
                     : 0ULL;
            }
            asm volatile("s_waitcnt lgkmcnt(0)" ::: "memory");   // kbArr visible
            __builtin_amdgcn_s_barrier();
            __builtin_amdgcn_sched_barrier(0);
        }
    } else {
        const int w1 = wave - 1;                 // 0..7
        const int slot = tid & 7;                // word offset within this wave's 8
        const int chunk = (tid >> 3) & 7;        // row class (rows chunk+8k)
        for (int b = 0; b < nblk; ++b) {
            if (b >= 1) {
                const u64 kb = kbArr[b - 1];     // written iter b-1, barrier-separated
                const int W = b + 1 + (w1 << 3) + slot;
                if (kb != 0ULL && W < 64) {      // W uniform across chunk-partners
                    const u64* rowbase = mask + ((size_t)(b - 1) << 12);
                    u64 acc = 0ULL;
#pragma unroll
                    for (int k = 0; k < 8; ++k) {
                        const int r = chunk + (k << 3);
                        u64 v = rowbase[((size_t)r << 6) + W];   // 64B/8-lane coalesced
                        acc |= (((kb >> r) & 1ULL) ? v : 0ULL);
                    }
                    acc |= __shfl_xor(acc, 8);
                    acc |= __shfl_xor(acc, 16);
                    acc |= __shfl_xor(acc, 32);
                    if (chunk == 0) remvArr[W] |= acc;   // sole writer of W this iter
                }
            }
            asm volatile("s_waitcnt lgkmcnt(0)" ::: "memory");
            __builtin_amdgcn_s_barrier();
            __builtin_amdgcn_sched_barrier(0);
        }
    }
}

__global__ __launch_bounds__(256) void k_out(const float* __restrict__ sx1, const float* __restrict__ sy1,
                                             const float* __restrict__ sx2, const float* __restrict__ sy2,
                                             const float* __restrict__ sconf,
                                             const int* __restrict__ Mp,
                                             const u64* __restrict__ keepw,
                                             float* __restrict__ out) {
    const int g = blockIdx.x * 256 + threadIdx.x;
    if (g >= NBOX * 5) return;
    const int r = g / 5;
    const int c = g - r * 5;
    const int M = *Mp;
    bool kept = false;
    if (r < M) kept = ((keepw[r >> 6] >> (r & 63)) & 1ULL) != 0ULL;
    float v = 0.0f;
    if (kept) {
        const float* arr = (c == 0) ? sx1 : (c == 1) ? sy1 : (c == 2) ? sx2 : (c == 3) ? sy2 : sconf;
        v = arr[r];
    }
    out[g] = v;
}

extern "C" void kernel_launch(void* const* d_in, const int* in_sizes, int n_in,
                              void* d_out, int out_size, void* d_ws, size_t ws_size,
                              hipStream_t stream) {
    const float* raw = (const float*)d_in[0];
    char* ws = (char*)d_ws;
    float* sx1 = (float*)(ws + 0);
    float* sy1 = (float*)(ws + 16384);
    float* sx2 = (float*)(ws + 32768);
    float* sy2 = (float*)(ws + 49152);
    float* sconf = (float*)(ws + 65536);
    int* Mp = (int*)(ws + 81920);
    u64* keepw = (u64*)(ws + 82432);
    u64* diagR = (u64*)(ws + 86016);
    u64* mask = (u64*)(ws + 131072);
    int* rank_partial = (int*)(ws + 2228224);
    float* out = (float*)d_out;

    k_rank<<<dim3(16, 16), dim3(256), 0, stream>>>(raw, rank_partial, Mp);
    k_scatter<<<dim3(16), dim3(256), 0, stream>>>(raw, rank_partial, sx1, sy1, sx2, sy2, sconf, Mp);
    k_mask<<<dim3(16, 64), dim3(256), 0, stream>>>(sx1, sy1, sx2, sy2, Mp, mask, diagR);
    k_scan<<<dim3(1), dim3(576), 0, stream>>>(Mp, mask, diagR, keepw);
    k_out<<<dim3(80), dim3(256), 0, stream>>>(sx1, sy1, sx2, sy2, sconf, Mp, keepw, out);
}

// Round 8
// 87.396 us; speedup vs baseline: 4.5277x; 1.0483x over previous
//
#include <hip/hip_runtime.h>
#include <stdint.h>

#define NBOX 4096
#define IMG 640.0f

typedef unsigned long long u64;
typedef unsigned int u32;

// ws layout (bytes):
//   [0      .. 16384)    sx1   (4096 f32, sorted)
//   [16384  .. 32768)    sy1
//   [32768  .. 49152)    sx2
//   [49152  .. 65536)    sy2
//   [65536  .. 81920)    sconf
//   [81920  .. 81924)    M (int, zeroed by k_rank blk(0,0); k_scatter accumulates)
//   [86016  .. 118784)   diagR (4096 u64): row r's suppression word within its own diagonal block
//   [131072 .. 2228224)  suppression mask (4096 rows x 64 u64 words = 2 MB)
//   [2228224 .. 2490368) rank_partial (16 x 4096 int = 256 KB)

// Grid (16 i-chunks, 16 j-chunks), 256 thr. Partial rank of i within j-chunk.
__global__ __launch_bounds__(256) void k_rank(const float* __restrict__ raw,
                                              int* __restrict__ rank_partial, int* __restrict__ Mp) {
    const int bi = blockIdx.x, bj = blockIdx.y;
    const int t = threadIdx.x;
    const int i = bi * 256 + t;
    if (bi == 0 && bj == 0 && t == 0) *Mp = 0;
    __shared__ float cj[256];
    cj[t] = raw[(bj * 256 + t) * 5 + 4];
    __syncthreads();

    const float ci = raw[i * 5 + 4];
    const int jbase = bj * 256;
    int rank = 0;
    const float4* c4 = reinterpret_cast<const float4*>(cj);
#pragma unroll 4
    for (int j4 = 0; j4 < 64; ++j4) {
        float4 c = c4[j4];
        int j = jbase + j4 * 4;
        rank += (c.x > ci || (c.x == ci && (j + 0) < i)) ? 1 : 0;
        rank += (c.y > ci || (c.y == ci && (j + 1) < i)) ? 1 : 0;
        rank += (c.z > ci || (c.z == ci && (j + 2) < i)) ? 1 : 0;
        rank += (c.w > ci || (c.w == ci && (j + 3) < i)) ? 1 : 0;
    }
    rank_partial[bj * NBOX + i] = rank;
}

__global__ __launch_bounds__(256) void k_scatter(const float* __restrict__ raw,
                                                 const int* __restrict__ rank_partial,
                                                 float* __restrict__ sx1, float* __restrict__ sy1,
                                                 float* __restrict__ sx2, float* __restrict__ sy2,
                                                 float* __restrict__ sconf, int* __restrict__ Mp) {
    const int i = blockIdx.x * 256 + threadIdx.x;
    const float ci = raw[i * 5 + 4];
    const bool vi = (ci >= 0.5f);

    int rank = 0;
#pragma unroll
    for (int k = 0; k < 16; ++k) rank += rank_partial[k * NBOX + i];

    u64 bal = __ballot(vi);
    if ((threadIdx.x & 63) == 0) atomicAdd(Mp, (int)__popcll(bal));

    if (vi) {
        // Strict IEEE ops (no FMA contraction) to match the numpy-evaluated reference.
        float cx = __fmul_rn(raw[i * 5 + 0], IMG);
        float cy = __fmul_rn(raw[i * 5 + 1], IMG);
        float w  = __fmul_rn(raw[i * 5 + 2], IMG);
        float h  = __fmul_rn(raw[i * 5 + 3], IMG);
        float hw = __fmul_rn(w, 0.5f);
        float hh = __fmul_rn(h, 0.5f);
        sx1[rank]   = __fsub_rn(cx, hw);
        sy1[rank]   = __fsub_rn(cy, hh);
        sx2[rank]   = __fadd_rn(cx, hw);
        sy2[rank]   = __fadd_rn(cy, hh);
        sconf[rank] = ci;
    }
}

// Block (bx, w): rows r = bx*256+tid (lane = row -> coalesced), word w of columns.
__global__ __launch_bounds__(256) void k_mask(const float* __restrict__ sx1, const float* __restrict__ sy1,
                                              const float* __restrict__ sx2, const float* __restrict__ sy2,
                                              const int* __restrict__ Mp,
                                              u64* __restrict__ mask, u64* __restrict__ diagR) {
    const int w = blockIdx.y;                      // column word 0..63
    const int r = blockIdx.x * 256 + threadIdx.x;  // row 0..4095
    const int t = threadIdx.x;
    const int M = *Mp;

    __shared__ float cx1[64], cy1[64], cx2[64], cy2[64], car[64];
    if (t < 64) {
        int j = (w << 6) + t;
        float a1 = sx1[j], b1 = sy1[j], a2 = sx2[j], b2 = sy2[j];
        cx1[t] = a1; cy1[t] = b1; cx2[t] = a2; cy2[t] = b2;
        car[t] = __fmul_rn(__fsub_rn(a2, a1), __fsub_rn(b2, b1));
    }
    __syncthreads();

    u64 bits = 0ULL;
    if (r < M) {
        const float x1 = sx1[r], y1 = sy1[r], x2 = sx2[r], y2 = sy2[r];
        const float area_i = __fmul_rn(__fsub_rn(x2, x1), __fsub_rn(y2, y1));
        const int bmax = min(64, M - (w << 6));       // j < M
        const int bmin = max(0, r + 1 - (w << 6));    // j > r
        for (int b = bmin; b < bmax; ++b) {
            float xx1 = fmaxf(x1, cx1[b]);
            float yy1 = fmaxf(y1, cy1[b]);
            float xx2 = fminf(x2, cx2[b]);
            float yy2 = fminf(y2, cy2[b]);
            float iw = fmaxf(__fsub_rn(xx2, xx1), 0.0f);
            float ih = fmaxf(__fsub_rn(yy2, yy1), 0.0f);
            float inter = __fmul_rn(iw, ih);
            float uni = __fsub_rn(__fadd_rn(area_i, car[b]), inter);
            float iou = __fdiv_rn(inter, fmaxf(uni, 1e-9f));
            if (iou > 0.5f) bits |= (1ULL << b);
        }
        mask[((size_t)r << 6) + w] = bits;
    }

    // diagonal block: row r's own-word suppression bits (0 for r >= M)
    if ((r >> 6) == w) diagR[r] = bits;
}

// 9 waves, 1 KiB LDS, one barrier per 64-box block, fused output epilogue.
//   wave 0 : resolve block b via scalar readlane over prefetched diagR rows;
//            carry to word b+1 accumulated IN the resolve loop from a
//            prefetched column register (no shfl chain).
//   waves 1-8: propagate block b-1's kept rows into remvArr[b+1..63] using
//            global-mask gathers PREFETCHED one iteration ahead (latency
//            crosses the barrier in flight).
__global__ __launch_bounds__(576) void k_scan(const int* __restrict__ Mp,
                                              const u64* __restrict__ mask,
                                              const u64* __restrict__ diagR,
                                              const float* __restrict__ sx1, const float* __restrict__ sy1,
                                              const float* __restrict__ sx2, const float* __restrict__ sy2,
                                              const float* __restrict__ sconf,
                                              float* __restrict__ out) {
    __shared__ u64 remvArr[64];
    __shared__ u64 kbArr[64];
    const int tid = threadIdx.x;
    const int wave = tid >> 6;
    const int lane = tid & 63;
    const int M = *Mp;
    const int nblk = (M + 63) >> 6;

    if (tid < 64) { remvArr[tid] = 0ULL; kbArr[tid] = 0ULL; }

    if (nblk > 0) {
        if (wave == 0) {
            __builtin_amdgcn_s_setprio(1);               // critical-path wave
            u64 rv = diagR[lane];                        // block 0 diag rows
            u32 rlo = (u32)rv, rhi = (u32)(rv >> 32);
            u64 cv = (nblk > 1) ? mask[((size_t)lane << 6) + 1] : 0ULL;  // col 1 of block-0 rows
            u32 clo = (u32)cv, chi = (u32)(cv >> 32);
            u64 carry = 0ULL;                            // block (b-1) -> word b suppression

            for (int b = 0; b < nblk; ++b) {
                u64 rb = remvArr[b];                     // blocks <= b-2 via bg, b-1 via carry
                const int rem = M - (b << 6);
                const u64 valid = (rem >= 64) ? ~0ULL : ((1ULL << rem) - 1ULL);
                u64 alive = valid & ~(rb | carry);
                u64 kb = 0ULL, car = 0ULL;
                while (alive) {                          // uniform; iterate kept boxes only
                    int i = __builtin_ctzll(alive);
                    alive &= alive - 1;
                    kb |= (1ULL << i);
                    u32 lo = __builtin_amdgcn_readlane(rlo, i);
                    u32 hi = __builtin_amdgcn_readlane(rhi, i);
                    u32 cl = __builtin_amdgcn_readlane(clo, i);   // off the serial chain
                    u32 ch = __builtin_amdgcn_readlane(chi, i);
                    alive &= ~(((u64)hi << 32) | (u64)lo);        // row i: bits only > i
                    car |= (((u64)ch << 32) | (u64)cl);           // row i's word b+1
                }
                carry = car;
                if (lane == 0) kbArr[b] = kb;

                // prefetch block b+1's diag rows + its carry column (word b+2)
                if (b + 1 < nblk) {
                    u64 nrv = diagR[((b + 1) << 6) + lane];
                    rlo = (u32)nrv; rhi = (u32)(nrv >> 32);
                    u64 ncv = (b + 2 < nblk)
                            ? mask[(((size_t)(b + 1) << 6) + lane) * 64 + (b + 2)]
                            : 0ULL;
                    clo = (u32)ncv; chi = (u32)(ncv >> 32);
                }
                asm volatile("s_waitcnt lgkmcnt(0)" ::: "memory");   // kbArr visible
                __builtin_amdgcn_s_barrier();
                __builtin_amdgcn_sched_barrier(0);
            }
        } else {
            const int w1 = wave - 1;                 // 0..7
            const int slot = tid & 7;                // word offset within this wave's 8
            const int chunk = (tid >> 3) & 7;        // row class (rows chunk+8k)
            u64 v[8];                                // prefetched gather, 1 iter ahead
            for (int b = 0; b < nblk; ++b) {
                if (b >= 1) {
                    const u64 kb = kbArr[b - 1];     // written iter b-1, barrier-separated
                    const int W = b + 1 + (w1 << 3) + slot;
                    if (kb != 0ULL && W < 64) {      // uniform across shfl partners
                        u64 acc = 0ULL;
#pragma unroll
                        for (int k = 0; k < 8; ++k) {
                            const int r = chunk + (k << 3);
                            acc |= (((kb >> r) & 1ULL) ? v[k] : 0ULL);
                        }
                        acc |= __shfl_xor(acc, 8);
                        acc |= __shfl_xor(acc, 16);
                        acc |= __shfl_xor(acc, 32);
                        if (chunk == 0) remvArr[W] |= acc;   // sole writer of W this iter
                    }
                }
                // issue next iteration's gather: rows of block b, column b+2+...
                if (b + 1 < nblk) {
                    const int W2 = b + 2 + (w1 << 3) + slot;
                    const int Wc = (W2 < 64) ? W2 : 63;          // clamp; masked at use
                    const u64* rowbase = mask + ((size_t)b << 12);
#pragma unroll
                    for (int k = 0; k < 8; ++k) {
                        const int r = chunk + (k << 3);
                        v[k] = rowbase[((size_t)r << 6) + Wc];   // flies across barrier
                    }
                }
                asm volatile("s_waitcnt lgkmcnt(0)" ::: "memory");
                __builtin_amdgcn_s_barrier();
                __builtin_amdgcn_sched_barrier(0);
            }
        }
    }
    // ---- fused output epilogue (kbArr final; last loop iteration ended with barrier) ----
    if (nblk == 0) __builtin_amdgcn_s_barrier();     // degenerate: still need kbArr zeros visible
    for (int g = tid; g < NBOX * 5; g += 576) {
        const int r = g / 5;
        const int c = g - r * 5;
        bool kept = false;
        if (r < M) kept = ((kbArr[r >> 6] >> (r & 63)) & 1ULL) != 0ULL;
        float vv = 0.0f;
        if (kept) {
            const float* arr = (c == 0) ? sx1 : (c == 1) ? sy1 : (c == 2) ? sx2 : (c == 3) ? sy2 : sconf;
            vv = arr[r];
        }
        out[g] = vv;
    }
}

extern "C" void kernel_launch(void* const* d_in, const int* in_sizes, int n_in,
                              void* d_out, int out_size, void* d_ws, size_t ws_size,
                              hipStream_t stream) {
    const float* raw = (const float*)d_in[0];
    char* ws = (char*)d_ws;
    float* sx1 = (float*)(ws + 0);
    float* sy1 = (float*)(ws + 16384);
    float* sx2 = (float*)(ws + 32768);
    float* sy2 = (float*)(ws + 49152);
    float* sconf = (float*)(ws + 65536);
    int* Mp = (int*)(ws + 81920);
    u64* diagR = (u64*)(ws + 86016);
    u64* mask = (u64*)(ws + 131072);
    int* rank_partial = (int*)(ws + 2228224);
    float* out = (float*)d_out;

    k_rank<<<dim3(16, 16), dim3(256), 0, stream>>>(raw, rank_partial, Mp);
    k_scatter<<<dim3(16), dim3(256), 0, stream>>>(raw, rank_partial, sx1, sy1, sx2, sy2, sconf, Mp);
    k_mask<<<dim3(16, 64), dim3(256), 0, stream>>>(sx1, sy1, sx2, sy2, Mp, mask, diagR);
    k_scan<<<dim3(1), dim3(576), 0, stream>>>(Mp, mask, diagR, sx1, sy1, sx2, sy2, sconf, out);
}

// Round 9
// 79.815 us; speedup vs baseline: 4.9577x; 1.0950x over previous
//
#include <hip/hip_runtime.h>
#include <stdint.h>

#define NBOX 4096
#define IMG 640.0f

typedef unsigned long long u64;
typedef unsigned int u32;

// ws layout (bytes):
//   [0      .. 16384)    sx1   (4096 f32, sorted)
//   [16384  .. 32768)    sy1
//   [32768  .. 49152)    sx2
//   [49152  .. 65536)    sy2
//   [65536  .. 81920)    sconf
//   [81920  .. 81924)    M (int, zeroed by k_rank blk(0,0); k_scatter accumulates)
//   [86016  .. 118784)   diagR (4096 u64): row r's suppression word within its own diagonal block
//   [131072 .. 2228224)  maskT (COLUMN-major: maskT[word][row], 64 x 4096 u64 = 2 MB)
//   [2228224 .. 2490368) rank_partial (16 x 4096 int = 256 KB)

// Grid (16 i-chunks, 16 j-chunks), 256 thr. Partial rank of i within j-chunk.
__global__ __launch_bounds__(256) void k_rank(const float* __restrict__ raw,
                                              int* __restrict__ rank_partial, int* __restrict__ Mp) {
    const int bi = blockIdx.x, bj = blockIdx.y;
    const int t = threadIdx.x;
    const int i = bi * 256 + t;
    if (bi == 0 && bj == 0 && t == 0) *Mp = 0;
    __shared__ float cj[256];
    cj[t] = raw[(bj * 256 + t) * 5 + 4];
    __syncthreads();

    const float ci = raw[i * 5 + 4];
    const int jbase = bj * 256;
    int rank = 0;
    const float4* c4 = reinterpret_cast<const float4*>(cj);
#pragma unroll 4
    for (int j4 = 0; j4 < 64; ++j4) {
        float4 c = c4[j4];
        int j = jbase + j4 * 4;
        rank += (c.x > ci || (c.x == ci && (j + 0) < i)) ? 1 : 0;
        rank += (c.y > ci || (c.y == ci && (j + 1) < i)) ? 1 : 0;
        rank += (c.z > ci || (c.z == ci && (j + 2) < i)) ? 1 : 0;
        rank += (c.w > ci || (c.w == ci && (j + 3) < i)) ? 1 : 0;
    }
    rank_partial[bj * NBOX + i] = rank;
}

__global__ __launch_bounds__(256) void k_scatter(const float* __restrict__ raw,
                                                 const int* __restrict__ rank_partial,
                                                 float* __restrict__ sx1, float* __restrict__ sy1,
                                                 float* __restrict__ sx2, float* __restrict__ sy2,
                                                 float* __restrict__ sconf, int* __restrict__ Mp) {
    const int i = blockIdx.x * 256 + threadIdx.x;
    const float ci = raw[i * 5 + 4];
    const bool vi = (ci >= 0.5f);

    int rank = 0;
#pragma unroll
    for (int k = 0; k < 16; ++k) rank += rank_partial[k * NBOX + i];

    u64 bal = __ballot(vi);
    if ((threadIdx.x & 63) == 0) atomicAdd(Mp, (int)__popcll(bal));

    if (vi) {
        // Strict IEEE ops (no FMA contraction) to match the numpy-evaluated reference.
        float cx = __fmul_rn(raw[i * 5 + 0], IMG);
        float cy = __fmul_rn(raw[i * 5 + 1], IMG);
        float w  = __fmul_rn(raw[i * 5 + 2], IMG);
        float h  = __fmul_rn(raw[i * 5 + 3], IMG);
        float hw = __fmul_rn(w, 0.5f);
        float hh = __fmul_rn(h, 0.5f);
        sx1[rank]   = __fsub_rn(cx, hw);
        sy1[rank]   = __fsub_rn(cy, hh);
        sx2[rank]   = __fadd_rn(cx, hw);
        sy2[rank]   = __fadd_rn(cy, hh);
        sconf[rank] = ci;
    }
}

// Block (bx, w): rows r = bx*256+tid, word w of columns. Column-major store ->
// maskT[w][r] contiguous in r = coalesced wave writes.
__global__ __launch_bounds__(256) void k_mask(const float* __restrict__ sx1, const float* __restrict__ sy1,
                                              const float* __restrict__ sx2, const float* __restrict__ sy2,
                                              const int* __restrict__ Mp,
                                              u64* __restrict__ maskT, u64* __restrict__ diagR) {
    const int w = blockIdx.y;                      // column word 0..63
    const int r = blockIdx.x * 256 + threadIdx.x;  // row 0..4095
    const int t = threadIdx.x;
    const int M = *Mp;

    __shared__ float cx1[64], cy1[64], cx2[64], cy2[64], car[64];
    if (t < 64) {
        int j = (w << 6) + t;
        float a1 = sx1[j], b1 = sy1[j], a2 = sx2[j], b2 = sy2[j];
        cx1[t] = a1; cy1[t] = b1; cx2[t] = a2; cy2[t] = b2;
        car[t] = __fmul_rn(__fsub_rn(a2, a1), __fsub_rn(b2, b1));
    }
    __syncthreads();

    u64 bits = 0ULL;
    if (r < M) {
        const float x1 = sx1[r], y1 = sy1[r], x2 = sx2[r], y2 = sy2[r];
        const float area_i = __fmul_rn(__fsub_rn(x2, x1), __fsub_rn(y2, y1));
        const int bmax = min(64, M - (w << 6));       // j < M
        const int bmin = max(0, r + 1 - (w << 6));    // j > r
        for (int b = bmin; b < bmax; ++b) {
            float xx1 = fmaxf(x1, cx1[b]);
            float yy1 = fmaxf(y1, cy1[b]);
            float xx2 = fminf(x2, cx2[b]);
            float yy2 = fminf(y2, cy2[b]);
            float iw = fmaxf(__fsub_rn(xx2, xx1), 0.0f);
            float ih = fmaxf(__fsub_rn(yy2, yy1), 0.0f);
            float inter = __fmul_rn(iw, ih);
            float uni = __fsub_rn(__fadd_rn(area_i, car[b]), inter);
            float iou = __fdiv_rn(inter, fmaxf(uni, 1e-9f));
            if (iou > 0.5f) bits |= (1ULL << b);
        }
        maskT[((size_t)w << 12) + r] = bits;          // coalesced column-major write
    }

    // diagonal block: row r's own-word suppression bits (0 for r >= M)
    if ((r >> 6) == w) diagR[r] = bits;
}

// 10 waves, ~5 KiB LDS, one barrier per 64-box block, fused output epilogue.
//   wave 0  : resolve block b (scalar readlane over diag rows + carry column,
//             both read from the LDS ring -- NO global loads on this wave).
//   waves 1-8: propagate block b-1's kept rows into remvArr[b+1..63]; coalesced
//             column-major gathers prefetched one iteration ahead.
//   wave 9  : prefetcher. global->reg->LDS ring (depth 4), 2 blocks ahead.
__global__ __launch_bounds__(640) void k_scan(const int* __restrict__ Mp,
                                              const u64* __restrict__ maskT,
                                              const u64* __restrict__ diagR,
                                              const float* __restrict__ sx1, const float* __restrict__ sy1,
                                              const float* __restrict__ sx2, const float* __restrict__ sy2,
                                              const float* __restrict__ sconf,
                                              float* __restrict__ out) {
    __shared__ u64 remvArr[64];
    __shared__ u64 kbArr[64];
    __shared__ u64 dbuf[4][64];   // diag rows of block p (ring slot p&3)
    __shared__ u64 cbuf[4][64];   // carry column (block p rows, word p+1)
    const int tid = threadIdx.x;
    const int wave = tid >> 6;
    const int lane = tid & 63;
    const int M = *Mp;
    const int nblk = (M + 63) >> 6;

    if (tid < 64) { remvArr[tid] = 0ULL; kbArr[tid] = 0ULL; }

    if (nblk > 0) {
        if (wave == 9) {
            // prologue: fill ring slots 0,1 and preload block 2 into regs
            u64 d0 = diagR[lane];
            u64 c0 = maskT[(1ULL << 12) + lane];                       // block0 rows, word 1
            u64 d1 = 0, c1 = 0;
            if (1 < nblk) {
                d1 = diagR[64 + lane];
                c1 = maskT[(2ULL << 12) + 64 + lane];                  // block1 rows, word 2
            }
            dbuf[0][lane] = d0; cbuf[0][lane] = c0;
            dbuf[1][lane] = d1; cbuf[1][lane] = c1;
        }
        asm volatile("s_waitcnt lgkmcnt(0)" ::: "memory");
        __builtin_amdgcn_s_barrier();
        __builtin_amdgcn_sched_barrier(0);

        if (wave == 0) {
            __builtin_amdgcn_s_setprio(1);               // critical-path wave
            u64 dv = dbuf[0][lane], cv = cbuf[0][lane];
            u32 rlo = (u32)dv, rhi = (u32)(dv >> 32);
            u32 clo = (u32)cv, chi = (u32)(cv >> 32);
            u64 carry = 0ULL;                            // block (b-1) -> word b suppression

            for (int b = 0; b < nblk; ++b) {
                u64 rb = remvArr[b];                     // blocks <= b-2 via bg, b-1 via carry
                const int rem = M - (b << 6);
                const u64 valid = (rem >= 64) ? ~0ULL : ((1ULL << rem) - 1ULL);
                u64 alive = valid & ~(rb | carry);
                u64 kb = 0ULL, car = 0ULL;
                while (alive) {                          // uniform; iterate kept boxes only
                    int i = __builtin_ctzll(alive);
                    alive &= alive - 1;
                    kb |= (1ULL << i);
                    u32 lo = __builtin_amdgcn_readlane(rlo, i);
                    u32 hi = __builtin_amdgcn_readlane(rhi, i);
                    u32 cl = __builtin_amdgcn_readlane(clo, i);   // off the serial chain
                    u32 ch = __builtin_amdgcn_readlane(chi, i);
                    alive &= ~(((u64)hi << 32) | (u64)lo);        // row i: bits only > i
                    car |= (((u64)ch << 32) | (u64)cl);           // row i's word b+1
                }
                carry = car;
                if (lane == 0) kbArr[b] = kb;

                if (b + 1 < nblk) {                      // next iter's regs from LDS ring
                    u64 nd = dbuf[(b + 1) & 3][lane];
                    u64 nc = cbuf[(b + 1) & 3][lane];
                    rlo = (u32)nd; rhi = (u32)(nd >> 32);
                    clo = (u32)nc; chi = (u32)(nc >> 32);
                }
                asm volatile("s_waitcnt lgkmcnt(0)" ::: "memory");   // kbArr visible
                __builtin_amdgcn_s_barrier();
                __builtin_amdgcn_sched_barrier(0);
            }
        } else if (wave == 9) {
            // pending regs: block 2 (issued in prologue epoch below), written at iter 0
            u64 d_pend = 0, c_pend = 0;
            if (2 < nblk) {
                d_pend = diagR[(2 << 6) + lane];
                c_pend = (3 < 64) ? maskT[(3ULL << 12) + (2 << 6) + lane] : 0ULL;
            }
            for (int b = 0; b < nblk; ++b) {
                const int nb = b + 2;
                if (nb < nblk) {                         // write ring slot for iter b+2
                    dbuf[nb & 3][lane] = d_pend;         // compiler inserts vmcnt wait
                    cbuf[nb & 3][lane] = c_pend;
                }
                const int fb = b + 3;                    // issue loads for iter b+3
                if (fb < nblk) {
                    d_pend = diagR[(fb << 6) + lane];
                    c_pend = (fb + 1 < 64) ? maskT[((size_t)(fb + 1) << 12) + (fb << 6) + lane] : 0ULL;
                }
                asm volatile("s_waitcnt lgkmcnt(0)" ::: "memory");
                __builtin_amdgcn_s_barrier();
                __builtin_amdgcn_sched_barrier(0);
            }
        } else {
            const int w1 = wave - 1;                 // 0..7
            const int chunk = tid & 7;               // row offset class -> coalesced lanes
            const int slot = (tid >> 3) & 7;         // word offset within this wave's 8
            u64 v[8];                                // prefetched gather, 1 iter ahead
            for (int b = 0; b < nblk; ++b) {
                if (b >= 1) {
                    const u64 kb = kbArr[b - 1];     // written iter b-1, barrier-separated
                    const int W = b + 1 + (w1 << 3) + slot;
                    if (kb != 0ULL && W < 64) {      // uniform across shfl partners
                        u64 acc = 0ULL;
#pragma unroll
                        for (int k = 0; k < 8; ++k) {
                            const int r = chunk + (k << 3);
                            acc |= (((kb >> r) & 1ULL) ? v[k] : 0ULL);
                        }
                        acc |= __shfl_xor(acc, 1);
                        acc |= __shfl_xor(acc, 2);
                        acc |= __shfl_xor(acc, 4);
                        if (chunk == 0) remvArr[W] |= acc;   // sole writer of W this iter
                    }
                }
                // issue next iteration's gather: block b rows, word b+2+...
                if (b + 1 < nblk) {
                    const int W2 = b + 2 + (w1 << 3) + slot;
                    const int Wc = (W2 < 64) ? W2 : 63;          // clamp; masked at use
                    const u64* colbase = maskT + ((size_t)Wc << 12) + ((size_t)b << 6);
#pragma unroll
                    for (int k = 0; k < 8; ++k)
                        v[k] = colbase[chunk + (k << 3)];        // coalesced; flies across barrier
                }
                asm volatile("s_waitcnt lgkmcnt(0)" ::: "memory");
                __builtin_amdgcn_s_barrier();
                __builtin_amdgcn_sched_barrier(0);
            }
        }
    }
    // ---- fused output epilogue (kbArr final; last loop iteration ended with barrier) ----
    if (nblk == 0) {
        asm volatile("s_waitcnt lgkmcnt(0)" ::: "memory");
        __builtin_amdgcn_s_barrier();     // degenerate: kbArr zeros visible
    }
    for (int g = tid; g < NBOX * 5; g += 640) {
        const int r = g / 5;
        const int c = g - r * 5;
        bool kept = false;
        if (r < M) kept = ((kbArr[r >> 6] >> (r & 63)) & 1ULL) != 0ULL;
        float vv = 0.0f;
        if (kept) {
            const float* arr = (c == 0) ? sx1 : (c == 1) ? sy1 : (c == 2) ? sx2 : (c == 3) ? sy2 : sconf;
            vv = arr[r];
        }
        out[g] = vv;
    }
}

extern "C" void kernel_launch(void* const* d_in, const int* in_sizes, int n_in,
                              void* d_out, int out_size, void* d_ws, size_t ws_size,
                              hipStream_t stream) {
    const float* raw = (const float*)d_in[0];
    char* ws = (char*)d_ws;
    float* sx1 = (float*)(ws + 0);
    float* sy1 = (float*)(ws + 16384);
    float* sx2 = (float*)(ws + 32768);
    float* sy2 = (float*)(ws + 49152);
    float* sconf = (float*)(ws + 65536);
    int* Mp = (int*)(ws + 81920);
    u64* diagR = (u64*)(ws + 86016);
    u64* maskT = (u64*)(ws + 131072);
    int* rank_partial = (int*)(ws + 2228224);
    float* out = (float*)d_out;

    k_rank<<<dim3(16, 16), dim3(256), 0, stream>>>(raw, rank_partial, Mp);
    k_scatter<<<dim3(16), dim3(256), 0, stream>>>(raw, rank_partial, sx1, sy1, sx2, sy2, sconf, Mp);
    k_mask<<<dim3(16, 64), dim3(256), 0, stream>>>(sx1, sy1, sx2, sy2, Mp, maskT, diagR);
    k_scan<<<dim3(1), dim3(640), 0, stream>>>(Mp, maskT, diagR, sx1, sy1, sx2, sy2, sconf, out);
}